// Round 6
// baseline (415.059 us; speedup 1.0000x reference)
//
#include <hip/hip_runtime.h>

// Cost volume: out[b, dy*9+dx, h, w] = leaky( mean_c c1[b,c,h,w] * warped[b,c,h+dy-4,w+dx-4] )
// B=8 C=192 H=128 W=160, 81 offsets, fp32, zero-padded borders.
//
// R9 = WPT 4->8 (12 FMA per load vs 9; L1 demand 4.5->3.4 GB) + CSPLIT=2
// (lane l / l+32 each sum 96 channels; combine = 72 shfl_xor(32)+add) +
// launch_bounds(256,2) so the 140-reg footprint CANNOT trigger the
// register-pressure deflation seen in R7/R8 (VGPR stuck at 60 => the 3-set
// pipeline never materialized) nor the R5 spill (cap-84 -> scratch).
// Depth-2 named pipeline (sets A/B) with sched_barrier(0) fences at
// issue/compute block granularity. XCD pinning (b = blockIdx&7) kept:
// FETCH 579->128 MB in R7. saddr addressing + mask-free inner loop kept.
//
// Guards: VGPR must land ~130-160 (pipeline real); WRITE_SIZE must stay
// ~52 MB (no spill). If VGPR <= 80 again -> next round uses inline-asm loads.
//
// Edges: W via clamped o0/o3 loads; garbage confined to acc[dx][j] with
// window col s=j+dx outside the image (s<4 at g==0, s>=12 at g==19), zeroed
// in the epilogue. H via clamped row + vrow-zeroed epilogue (zero-padded ref).

namespace {
constexpr int SR  = 4;
constexpr int MO  = 9;               // 2*SR+1
constexpr int NB  = 8;
constexpr int NC  = 192;
constexpr int CSPLIT = 2;
constexpr int CPL = NC / CSPLIT;     // 96 channels per lane
constexpr int NH  = 128;
constexpr int NW  = 160;
constexpr int HW  = NH * NW;
constexpr int WPT = 8;               // w pixels per unit
constexpr int NG  = NW / WPT;        // 20 w-groups
constexpr int UPH = MO * NG;         // 180 units per (b,h)
constexpr int NT  = 256;
constexpr int UPB = NT / CSPLIT;     // 128 units per block
constexpr int UNITS = NB * NH * UPH; // 184320
constexpr int NBLK  = UNITS / UPB;   // 1440 blocks = 8 batches x 180
}

__global__ __launch_bounds__(NT, 2)
void costvol_kernel(const float* __restrict__ c1,
                    const float* __restrict__ warped,
                    const float* __restrict__ alphap,
                    float* __restrict__ out)
{
    // XCD pinning: batch = blockIdx % 8 (one batch per XCD's L2).
    const int b    = blockIdx.x & (NB - 1);
    const int bb   = blockIdx.x >> 3;             // 0..179 within batch
    const int tid  = threadIdx.x;
    const int lane = tid & 63;
    const int wave = tid >> 6;
    const int chalf = lane >> 5;                  // which 96-channel half
    const int v    = bb * UPB + (wave << 5) + (lane & 31);  // unit 0..23039

    const int g  = v % NG;
    const int dy = (v / NG) % MO;
    const int h  = v / UPH;

    const int w0 = g * WPT;
    const int hr = h + dy - SR;
    const bool vrow = (unsigned)hr < (unsigned)NH;
    const int hrc = vrow ? hr : (hr < 0 ? 0 : NH - 1);

    // four aligned 16B loads covering w0-4 .. w0+11; edge lanes clamp the
    // OOB load in-row (garbage confined to known acc entries).
    const int o0 = (g == 0)      ? w0 : (w0 - 4);
    const int o3 = (g == NG - 1) ? w0 : (w0 + 8);
    const bool e0 = (g == 0);
    const bool e1 = (g == NG - 1);

    // uniform bases; per-lane 32-bit offsets computed once (saddr form)
    const size_t cb = ((size_t)b * NC + (size_t)chalf * CPL) * HW;
    const float* wB = warped + cb;
    const float* cB = c1     + cb;
    const int rw = hrc * NW;
    const int woff0 = rw + o0;
    const int woff1 = rw + w0;
    const int woff2 = rw + w0 + 4;
    const int woff3 = rw + o3;
    const int coff  = h * NW + w0;

    float acc[MO][WPT];
#pragma unroll
    for (int i = 0; i < MO; ++i)
#pragma unroll
        for (int j = 0; j < WPT; ++j) acc[i][j] = 0.0f;

    // named pipeline sets (registers, not scratch)
    float4 A0, A1, A2, A3, AC0, AC1;
    float4 B0, B1, B2, B3, BC0, BC1;

#define ISSUE(ch, X0, X1, X2, X3, XC0, XC1)                 \
    {                                                       \
        const float* wq = wB + (size_t)(ch) * HW;           \
        const float* cq = cB + (size_t)(ch) * HW;           \
        X0  = *(const float4*)(wq + woff0);                 \
        X1  = *(const float4*)(wq + woff1);                 \
        X2  = *(const float4*)(wq + woff2);                 \
        X3  = *(const float4*)(wq + woff3);                 \
        XC0 = *(const float4*)(cq + coff);                  \
        XC1 = *(const float4*)(cq + coff + 4);              \
    }

#define COMPUTE(X0, X1, X2, X3, XC0, XC1)                   \
    {                                                       \
        const float win[16] = {                             \
            X0.x, X0.y, X0.z, X0.w,  X1.x, X1.y, X1.z, X1.w,\
            X2.x, X2.y, X2.z, X2.w,  X3.x, X3.y, X3.z, X3.w};\
        const float cv[WPT] = { XC0.x, XC0.y, XC0.z, XC0.w, \
                                XC1.x, XC1.y, XC1.z, XC1.w };\
        _Pragma("unroll")                                   \
        for (int dx = 0; dx < MO; ++dx)                     \
            _Pragma("unroll")                               \
            for (int j = 0; j < WPT; ++j)                   \
                acc[dx][j] = fmaf(cv[j], win[j + dx], acc[dx][j]); \
    }

    // prologue: channels 0,1 in flight
    ISSUE(0, A0, A1, A2, A3, AC0, AC1);
    ISSUE(1, B0, B1, B2, B3, BC0, BC1);
    __builtin_amdgcn_sched_barrier(0);

#pragma unroll 1
    for (int c = 0; c < CPL - 2; c += 2) {
        COMPUTE(A0, A1, A2, A3, AC0, AC1);
        ISSUE(c + 2, A0, A1, A2, A3, AC0, AC1);
        __builtin_amdgcn_sched_barrier(0);
        COMPUTE(B0, B1, B2, B3, BC0, BC1);
        if (c + 3 < CPL) ISSUE(c + 3, B0, B1, B2, B3, BC0, BC1);
        __builtin_amdgcn_sched_barrier(0);
    }
    // tail: A holds CPL-2, B holds CPL-1
    COMPUTE(A0, A1, A2, A3, AC0, AC1);
    COMPUTE(B0, B1, B2, B3, BC0, BC1);

    // combine the two channel halves: wave-internal, no LDS, no barrier
#pragma unroll
    for (int dx = 0; dx < MO; ++dx)
#pragma unroll
        for (int j = 0; j < WPT; ++j)
            acc[dx][j] += __shfl_xor(acc[dx][j], 32);

    // epilogue (lower-half lanes): mean + leaky relu.
    //  - invalid warped row -> whole thread's outputs are 0
    //  - W-edge: acc[dx][j] with window col s=j+dx out of image -> exactly 0
    if (chalf == 0) {
        const float scale = 1.0f / (float)NC;
        const float al = alphap[0];
        float* op = out + ((size_t)b * (MO * MO) + (size_t)(dy * MO)) * HW
                        + (size_t)h * NW + w0;
#pragma unroll
        for (int dx = 0; dx < MO; ++dx) {
            float r[WPT];
#pragma unroll
            for (int j = 0; j < WPT; ++j) {
                const int s = j + dx;
                float vv = acc[dx][j] * scale;
                const bool bad = (!vrow) || (e0 && (s < 4)) || (e1 && (s >= 12));
                vv = bad ? 0.0f : vv;
                r[j] = (vv >= 0.0f) ? vv : al * vv;
            }
            float4* q = (float4*)(op + (size_t)dx * HW);
            q[0] = make_float4(r[0], r[1], r[2], r[3]);
            q[1] = make_float4(r[4], r[5], r[6], r[7]);
        }
    }
#undef ISSUE
#undef COMPUTE
}

extern "C" void kernel_launch(void* const* d_in, const int* in_sizes, int n_in,
                              void* d_out, int out_size, void* d_ws, size_t ws_size,
                              hipStream_t stream) {
    (void)in_sizes; (void)n_in; (void)out_size; (void)d_ws; (void)ws_size;
    const float* c1     = (const float*)d_in[0];
    const float* warped = (const float*)d_in[1];
    const float* alpha  = (const float*)d_in[2];
    float* out          = (float*)d_out;
    costvol_kernel<<<dim3(NBLK), dim3(NT), 0, stream>>>(c1, warped, alpha, out);
}